// Round 1
// baseline (32.270 us; speedup 1.0000x reference)
//
#include <hip/hip_runtime.h>

#define GRID_N 256

// ---------------------------------------------------------------------------
// Kernel 1: invert the 4x4 pose (Gauss-Jordan, single thread — pose is tiny).
// Stores rows of T_inv's top 3x4 ([R|t]) into ws (12 floats).
// ---------------------------------------------------------------------------
__global__ void pose_invert_kernel(const float* __restrict__ pose,
                                   float* __restrict__ tinv) {
    if (threadIdx.x != 0 || blockIdx.x != 0) return;
    float a[4][8];
    for (int i = 0; i < 4; ++i)
        for (int j = 0; j < 4; ++j) {
            a[i][j]     = pose[i * 4 + j];
            a[i][j + 4] = (i == j) ? 1.0f : 0.0f;
        }
    for (int c = 0; c < 4; ++c) {
        int piv = c;
        float best = fabsf(a[c][c]);
        for (int r = c + 1; r < 4; ++r) {
            float v = fabsf(a[r][c]);
            if (v > best) { best = v; piv = r; }
        }
        if (piv != c)
            for (int j = 0; j < 8; ++j) {
                float t = a[c][j]; a[c][j] = a[piv][j]; a[piv][j] = t;
            }
        float inv = 1.0f / a[c][c];
        for (int j = 0; j < 8; ++j) a[c][j] *= inv;
        for (int r = 0; r < 4; ++r) {
            if (r == c) continue;
            float f = a[r][c];
            for (int j = 0; j < 8; ++j) a[r][j] -= f * a[c][j];
        }
    }
    for (int i = 0; i < 3; ++i)
        for (int j = 0; j < 4; ++j)
            tinv[i * 4 + j] = a[i][j + 4];
}

// ---------------------------------------------------------------------------
// Kernel 2: trilinear SDF interpolation with searchsorted semantics.
// One point per thread. Coordinate grids staged in LDS; exact lower_bound
// (side='left') binary search; edge semantics match the JAX reference:
//   idx_r = min(lower_bound, n-1); idx_l = clamp(idx_r-1, 0, n-1)
//   dist_l = max(x - p[idx_l], 0); dist_r = max(p[idx_r] - x, 0)
//   both-zero -> (1,1)
// ---------------------------------------------------------------------------
__global__ __launch_bounds__(256) void sdf_interp_kernel(
    const float* __restrict__ sdf,
    const float* __restrict__ xg,
    const float* __restrict__ yg,
    const float* __restrict__ zg,
    const float* __restrict__ tinv,
    const float* __restrict__ pts,
    float* __restrict__ out,
    int K) {
    __shared__ float sx[GRID_N];
    __shared__ float sy[GRID_N];
    __shared__ float sz[GRID_N];
    sx[threadIdx.x] = xg[threadIdx.x];
    sy[threadIdx.x] = yg[threadIdx.x];
    sz[threadIdx.x] = zg[threadIdx.x];
    __syncthreads();

    const int i = blockIdx.x * blockDim.x + threadIdx.x;
    if (i >= K) return;

    // transform point: x_obj = R_inv * p + t_inv
    const float px = pts[3 * i + 0];
    const float py = pts[3 * i + 1];
    const float pz = pts[3 * i + 2];
    const float x = tinv[0] * px + tinv[1] * py + tinv[2]  * pz + tinv[3];
    const float y = tinv[4] * px + tinv[5] * py + tinv[6]  * pz + tinv[7];
    const float z = tinv[8] * px + tinv[9] * py + tinv[10] * pz + tinv[11];

    int ixl, ixr, iyl, iyr, izl, izr;
    float dlx, drx, dly, dry, dlz, drz;

    // per-axis searchsorted + distances (macro to keep everything in regs)
#define AXIS(P, V, IL, IR, DL, DR)                                        \
    {                                                                     \
        int lo = 0, hi = GRID_N;                                          \
        while (lo < hi) {                                                 \
            int mid = (lo + hi) >> 1;                                     \
            if (P[mid] < (V)) lo = mid + 1; else hi = mid;                \
        }                                                                 \
        int r = (lo >= GRID_N) ? (GRID_N - 1) : lo;                       \
        int l = (r - 1 < 0) ? 0 : (r - 1);                                \
        float dl = fmaxf((V) - P[l], 0.0f);                               \
        float dr = fmaxf(P[r] - (V), 0.0f);                               \
        if (dl == 0.0f && dr == 0.0f) { dl = 1.0f; dr = 1.0f; }           \
        IL = l; IR = r; DL = dl; DR = dr;                                 \
    }

    AXIS(sx, x, ixl, ixr, dlx, drx)
    AXIS(sy, y, iyl, iyr, dly, dry)
    AXIS(sz, z, izl, izr, dlz, drz)
#undef AXIS

    // corner weights: corner at idx_l gets dist_r (opposite side), etc.
    const int bx0 = ixl * (GRID_N * GRID_N);
    const int bx1 = ixr * (GRID_N * GRID_N);
    const int by0 = iyl * GRID_N;
    const int by1 = iyr * GRID_N;

    const float v000 = sdf[bx0 + by0 + izl];
    const float v001 = sdf[bx0 + by0 + izr];
    const float v010 = sdf[bx0 + by1 + izl];
    const float v011 = sdf[bx0 + by1 + izr];
    const float v100 = sdf[bx1 + by0 + izl];
    const float v101 = sdf[bx1 + by0 + izr];
    const float v110 = sdf[bx1 + by1 + izl];
    const float v111 = sdf[bx1 + by1 + izr];

    const float wz0 = drz, wz1 = dlz;
    const float wy0 = dry, wy1 = dly;
    const float wx0 = drx, wx1 = dlx;

    const float numer =
        wx0 * (wy0 * (v000 * wz0 + v001 * wz1) +
               wy1 * (v010 * wz0 + v011 * wz1)) +
        wx1 * (wy0 * (v100 * wz0 + v101 * wz1) +
               wy1 * (v110 * wz0 + v111 * wz1));

    const float denom = (dlx + drx) * (dly + dry) * (dlz + drz);
    out[i] = numer / denom;
}

// ---------------------------------------------------------------------------
extern "C" void kernel_launch(void* const* d_in, const int* in_sizes, int n_in,
                              void* d_out, int out_size, void* d_ws, size_t ws_size,
                              hipStream_t stream) {
    const float* sdf  = (const float*)d_in[0];
    const float* xg   = (const float*)d_in[1];
    const float* yg   = (const float*)d_in[2];
    const float* zg   = (const float*)d_in[3];
    const float* pose = (const float*)d_in[4];
    const float* pts  = (const float*)d_in[5];
    float* out = (float*)d_out;
    float* tinv = (float*)d_ws;  // 12 floats

    const int K = in_sizes[5] / 3;

    pose_invert_kernel<<<1, 64, 0, stream>>>(pose, tinv);

    const int block = 256;
    const int grid = (K + block - 1) / block;
    sdf_interp_kernel<<<grid, block, 0, stream>>>(sdf, xg, yg, zg, tinv, pts,
                                                  out, K);
}

// Round 2
// 31.710 us; speedup vs baseline: 1.0177x; 1.0177x over previous
//
#include <hip/hip_runtime.h>

#define GRID_N 256

// ---------------------------------------------------------------------------
// Kernel 1: invert the 4x4 pose (Gauss-Jordan, single thread — pose is tiny).
// Stores rows of T_inv's top 3x4 ([R|t]) into ws (12 floats).
// ---------------------------------------------------------------------------
__global__ void pose_invert_kernel(const float* __restrict__ pose,
                                   float* __restrict__ tinv) {
    if (threadIdx.x != 0 || blockIdx.x != 0) return;
    float a[4][8];
    for (int i = 0; i < 4; ++i)
        for (int j = 0; j < 4; ++j) {
            a[i][j]     = pose[i * 4 + j];
            a[i][j + 4] = (i == j) ? 1.0f : 0.0f;
        }
    for (int c = 0; c < 4; ++c) {
        int piv = c;
        float best = fabsf(a[c][c]);
        for (int r = c + 1; r < 4; ++r) {
            float v = fabsf(a[r][c]);
            if (v > best) { best = v; piv = r; }
        }
        if (piv != c)
            for (int j = 0; j < 8; ++j) {
                float t = a[c][j]; a[c][j] = a[piv][j]; a[piv][j] = t;
            }
        float inv = 1.0f / a[c][c];
        for (int j = 0; j < 8; ++j) a[c][j] *= inv;
        for (int r = 0; r < 4; ++r) {
            if (r == c) continue;
            float f = a[r][c];
            for (int j = 0; j < 8; ++j) a[r][j] -= f * a[c][j];
        }
    }
    for (int i = 0; i < 3; ++i)
        for (int j = 0; j < 4; ++j)
            tinv[i * 4 + j] = a[i][j + 4];
}

// ---------------------------------------------------------------------------
// Kernel 2: trilinear SDF interpolation, searchsorted(side='left') semantics.
// One point per thread. O(1) affine index guess + exact fixup (monotone-grid
// exact lower_bound; guess only needs to be close). Gathers issued as early
// as possible; weight math overlaps the vmcnt wait.
// ---------------------------------------------------------------------------
__global__ __launch_bounds__(256) void sdf_interp_kernel(
    const float* __restrict__ sdf,
    const float* __restrict__ xg,
    const float* __restrict__ yg,
    const float* __restrict__ zg,
    const float* __restrict__ tinv,
    const float* __restrict__ pts,
    float* __restrict__ out,
    int K) {
    __shared__ float sx[GRID_N];
    __shared__ float sy[GRID_N];
    __shared__ float sz[GRID_N];
    sx[threadIdx.x] = xg[threadIdx.x];
    sy[threadIdx.x] = yg[threadIdx.x];
    sz[threadIdx.x] = zg[threadIdx.x];
    __syncthreads();

    const int i = blockIdx.x * blockDim.x + threadIdx.x;
    if (i >= K) return;

    const float px = pts[3 * i + 0];
    const float py = pts[3 * i + 1];
    const float pz = pts[3 * i + 2];
    const float x = tinv[0] * px + tinv[1] * py + tinv[2]  * pz + tinv[3];
    const float y = tinv[4] * px + tinv[5] * py + tinv[6]  * pz + tinv[7];
    const float z = tinv[8] * px + tinv[9] * py + tinv[10] * pz + tinv[11];

    // exact lower_bound via affine guess + fixup. r = first idx with P[r] >= v
    // (clamped to GRID_N-1 when none), l = clamp(r-1, 0).
#define FIND(P, V, L, R)                                                  \
    int L, R;                                                             \
    {                                                                     \
        const float p0 = P[0];                                            \
        const float invh = 1.0f / (P[1] - p0);                            \
        int r = (int)ceilf(((V) - p0) * invh);                            \
        r = (r < 0) ? 0 : ((r > GRID_N - 1) ? GRID_N - 1 : r);            \
        while (r > 0 && P[r - 1] >= (V)) --r;                             \
        while (r < GRID_N - 1 && P[r] < (V)) ++r;                         \
        R = r;                                                            \
        L = (r > 0) ? r - 1 : 0;                                          \
    }

    FIND(sx, x, ixl, ixr)
    FIND(sy, y, iyl, iyr)
    FIND(sz, z, izl, izr)
#undef FIND

    // issue all 8 gathers immediately
    const int bx0 = ixl * (GRID_N * GRID_N);
    const int bx1 = ixr * (GRID_N * GRID_N);
    const int by0 = iyl * GRID_N;
    const int by1 = iyr * GRID_N;

    const float v000 = sdf[bx0 + by0 + izl];
    const float v001 = sdf[bx0 + by0 + izr];
    const float v010 = sdf[bx0 + by1 + izl];
    const float v011 = sdf[bx0 + by1 + izr];
    const float v100 = sdf[bx1 + by0 + izl];
    const float v101 = sdf[bx1 + by0 + izr];
    const float v110 = sdf[bx1 + by1 + izl];
    const float v111 = sdf[bx1 + by1 + izr];

    // distances / weights (overlaps the gather latency)
    float dlx = fmaxf(x - sx[ixl], 0.0f);
    float drx = fmaxf(sx[ixr] - x, 0.0f);
    if (dlx == 0.0f && drx == 0.0f) { dlx = 1.0f; drx = 1.0f; }
    float dly = fmaxf(y - sy[iyl], 0.0f);
    float dry = fmaxf(sy[iyr] - y, 0.0f);
    if (dly == 0.0f && dry == 0.0f) { dly = 1.0f; dry = 1.0f; }
    float dlz = fmaxf(z - sz[izl], 0.0f);
    float drz = fmaxf(sz[izr] - z, 0.0f);
    if (dlz == 0.0f && drz == 0.0f) { dlz = 1.0f; drz = 1.0f; }

    const float numer =
        drx * (dry * (v000 * drz + v001 * dlz) +
               dly * (v010 * drz + v011 * dlz)) +
        dlx * (dry * (v100 * drz + v101 * dlz) +
               dly * (v110 * drz + v111 * dlz));

    const float denom = (dlx + drx) * (dly + dry) * (dlz + drz);
    out[i] = numer / denom;
}

// ---------------------------------------------------------------------------
extern "C" void kernel_launch(void* const* d_in, const int* in_sizes, int n_in,
                              void* d_out, int out_size, void* d_ws, size_t ws_size,
                              hipStream_t stream) {
    const float* sdf  = (const float*)d_in[0];
    const float* xg   = (const float*)d_in[1];
    const float* yg   = (const float*)d_in[2];
    const float* zg   = (const float*)d_in[3];
    const float* pose = (const float*)d_in[4];
    const float* pts  = (const float*)d_in[5];
    float* out = (float*)d_out;
    float* tinv = (float*)d_ws;  // 12 floats

    const int K = in_sizes[5] / 3;

    pose_invert_kernel<<<1, 64, 0, stream>>>(pose, tinv);

    const int block = 256;
    const int grid = (K + block - 1) / block;
    sdf_interp_kernel<<<grid, block, 0, stream>>>(sdf, xg, yg, zg, tinv, pts,
                                                  out, K);
}

// Round 3
// 31.571 us; speedup vs baseline: 1.0222x; 1.0044x over previous
//
#include <hip/hip_runtime.h>

#define GRID_N 256

// 8-byte vector load with 4-byte alignment guarantee (z-pair may start at an
// odd index). Clang emits global_load_dwordx2 (unaligned global is supported
// on gfx950); worst case it splits into two dword loads (= previous code).
typedef float float2u __attribute__((ext_vector_type(2), aligned(4)));

// ---------------------------------------------------------------------------
// Kernel 1: invert the 4x4 pose (Gauss-Jordan, single thread — pose is tiny).
// ---------------------------------------------------------------------------
__global__ void pose_invert_kernel(const float* __restrict__ pose,
                                   float* __restrict__ tinv) {
    if (threadIdx.x != 0 || blockIdx.x != 0) return;
    float a[4][8];
    for (int i = 0; i < 4; ++i)
        for (int j = 0; j < 4; ++j) {
            a[i][j]     = pose[i * 4 + j];
            a[i][j + 4] = (i == j) ? 1.0f : 0.0f;
        }
    for (int c = 0; c < 4; ++c) {
        int piv = c;
        float best = fabsf(a[c][c]);
        for (int r = c + 1; r < 4; ++r) {
            float v = fabsf(a[r][c]);
            if (v > best) { best = v; piv = r; }
        }
        if (piv != c)
            for (int j = 0; j < 8; ++j) {
                float t = a[c][j]; a[c][j] = a[piv][j]; a[piv][j] = t;
            }
        float inv = 1.0f / a[c][c];
        for (int j = 0; j < 8; ++j) a[c][j] *= inv;
        for (int r = 0; r < 4; ++r) {
            if (r == c) continue;
            float f = a[r][c];
            for (int j = 0; j < 8; ++j) a[r][j] -= f * a[c][j];
        }
    }
    for (int i = 0; i < 3; ++i)
        for (int j = 0; j < 4; ++j)
            tinv[i * 4 + j] = a[i][j + 4];
}

// ---------------------------------------------------------------------------
// Kernel 2: trilinear SDF interpolation, searchsorted(side='left') semantics.
// One point per thread. Affine index guess + exact fixup. The two z-corners
// are adjacent floats -> fused into one 8B load (4 loads/point instead of 8).
// ---------------------------------------------------------------------------
__global__ __launch_bounds__(256) void sdf_interp_kernel(
    const float* __restrict__ sdf,
    const float* __restrict__ xg,
    const float* __restrict__ yg,
    const float* __restrict__ zg,
    const float* __restrict__ tinv,
    const float* __restrict__ pts,
    float* __restrict__ out,
    int K) {
    __shared__ float sx[GRID_N];
    __shared__ float sy[GRID_N];
    __shared__ float sz[GRID_N];
    sx[threadIdx.x] = xg[threadIdx.x];
    sy[threadIdx.x] = yg[threadIdx.x];
    sz[threadIdx.x] = zg[threadIdx.x];
    __syncthreads();

    const int i = blockIdx.x * blockDim.x + threadIdx.x;
    if (i >= K) return;

    const float px = pts[3 * i + 0];
    const float py = pts[3 * i + 1];
    const float pz = pts[3 * i + 2];
    const float x = tinv[0] * px + tinv[1] * py + tinv[2]  * pz + tinv[3];
    const float y = tinv[4] * px + tinv[5] * py + tinv[6]  * pz + tinv[7];
    const float z = tinv[8] * px + tinv[9] * py + tinv[10] * pz + tinv[11];

    // exact lower_bound via affine guess + fixup. r = first idx with P[r] >= v
    // (clamped to GRID_N-1), l = clamp(r-1, 0).
#define FIND(P, V, L, R)                                                  \
    int L, R;                                                             \
    {                                                                     \
        const float p0 = P[0];                                            \
        const float invh = 1.0f / (P[1] - p0);                            \
        int r = (int)ceilf(((V) - p0) * invh);                            \
        r = (r < 0) ? 0 : ((r > GRID_N - 1) ? GRID_N - 1 : r);            \
        while (r > 0 && P[r - 1] >= (V)) --r;                             \
        while (r < GRID_N - 1 && P[r] < (V)) ++r;                         \
        R = r;                                                            \
        L = (r > 0) ? r - 1 : 0;                                          \
    }

    FIND(sx, x, ixl, ixr)
    FIND(sy, y, iyl, iyr)
    FIND(sz, z, izl, izr)
#undef FIND

    // issue all 4 fused gathers immediately (z-pair = one 8B load)
    const int bx0 = ixl * (GRID_N * GRID_N);
    const int bx1 = ixr * (GRID_N * GRID_N);
    const int by0 = iyl * GRID_N;
    const int by1 = iyr * GRID_N;

    const float2u z00 = *(const float2u*)(sdf + bx0 + by0 + izl);
    const float2u z01 = *(const float2u*)(sdf + bx0 + by1 + izl);
    const float2u z10 = *(const float2u*)(sdf + bx1 + by0 + izl);
    const float2u z11 = *(const float2u*)(sdf + bx1 + by1 + izl);

    // distances / weights (overlaps the gather latency)
    float dlx = fmaxf(x - sx[ixl], 0.0f);
    float drx = fmaxf(sx[ixr] - x, 0.0f);
    if (dlx == 0.0f && drx == 0.0f) { dlx = 1.0f; drx = 1.0f; }
    float dly = fmaxf(y - sy[iyl], 0.0f);
    float dry = fmaxf(sy[iyr] - y, 0.0f);
    if (dly == 0.0f && dry == 0.0f) { dly = 1.0f; dry = 1.0f; }
    float dlz = fmaxf(z - sz[izl], 0.0f);
    float drz = fmaxf(sz[izr] - z, 0.0f);
    if (dlz == 0.0f && drz == 0.0f) { dlz = 1.0f; drz = 1.0f; }

    // izr == izl only when r == 0 (then the "right" corner equals index 0):
    const bool zsame = (izr == izl);
    const float v000 = z00.x, v001 = zsame ? z00.x : z00.y;
    const float v010 = z01.x, v011 = zsame ? z01.x : z01.y;
    const float v100 = z10.x, v101 = zsame ? z10.x : z10.y;
    const float v110 = z11.x, v111 = zsame ? z11.x : z11.y;

    const float numer =
        drx * (dry * (v000 * drz + v001 * dlz) +
               dly * (v010 * drz + v011 * dlz)) +
        dlx * (dry * (v100 * drz + v101 * dlz) +
               dly * (v110 * drz + v111 * dlz));

    const float denom = (dlx + drx) * (dly + dry) * (dlz + drz);
    out[i] = numer / denom;
}

// ---------------------------------------------------------------------------
extern "C" void kernel_launch(void* const* d_in, const int* in_sizes, int n_in,
                              void* d_out, int out_size, void* d_ws, size_t ws_size,
                              hipStream_t stream) {
    const float* sdf  = (const float*)d_in[0];
    const float* xg   = (const float*)d_in[1];
    const float* yg   = (const float*)d_in[2];
    const float* zg   = (const float*)d_in[3];
    const float* pose = (const float*)d_in[4];
    const float* pts  = (const float*)d_in[5];
    float* out = (float*)d_out;
    float* tinv = (float*)d_ws;  // 12 floats

    const int K = in_sizes[5] / 3;

    pose_invert_kernel<<<1, 64, 0, stream>>>(pose, tinv);

    const int block = 256;
    const int grid = (K + block - 1) / block;
    sdf_interp_kernel<<<grid, block, 0, stream>>>(sdf, xg, yg, zg, tinv, pts,
                                                  out, K);
}

// Round 4
// 25.644 us; speedup vs baseline: 1.2584x; 1.2311x over previous
//
#include <hip/hip_runtime.h>

#define GRID_N 256

// 8-byte vector load with 4-byte alignment (z-pair may start at odd index).
typedef float float2u __attribute__((ext_vector_type(2), aligned(4)));

// ---------------------------------------------------------------------------
// Single fused kernel:
//  - thread 0 of each block inverts the 4x4 pose (Gauss-Jordan) into LDS
//    (redundant per block, ~hundreds of cycles, removes a serialized launch)
//  - all threads stage the coordinate grids into LDS
//  - each thread processes TWO points (2x memory-level parallelism per wave)
//  - sdf gathers use nontemporal loads (bypass L1 allocation -> more
//    outstanding-miss headroom; L1 hit rate on random gathers is negligible)
// ---------------------------------------------------------------------------
__global__ __launch_bounds__(256) void sdf_interp_kernel(
    const float* __restrict__ sdf,
    const float* __restrict__ xg,
    const float* __restrict__ yg,
    const float* __restrict__ zg,
    const float* __restrict__ pose,
    const float* __restrict__ pts,
    float* __restrict__ out,
    int K) {
    __shared__ float sx[GRID_N];
    __shared__ float sy[GRID_N];
    __shared__ float sz[GRID_N];
    __shared__ float ti[12];

    if (threadIdx.x == 0) {
        // 4x4 Gauss-Jordan inverse (general, matches jnp.linalg.inv semantics)
        float a[4][8];
        for (int r = 0; r < 4; ++r)
            for (int c = 0; c < 4; ++c) {
                a[r][c]     = pose[r * 4 + c];
                a[r][c + 4] = (r == c) ? 1.0f : 0.0f;
            }
        for (int c = 0; c < 4; ++c) {
            int piv = c;
            float best = fabsf(a[c][c]);
            for (int r = c + 1; r < 4; ++r) {
                float v = fabsf(a[r][c]);
                if (v > best) { best = v; piv = r; }
            }
            if (piv != c)
                for (int j = 0; j < 8; ++j) {
                    float t = a[c][j]; a[c][j] = a[piv][j]; a[piv][j] = t;
                }
            float inv = 1.0f / a[c][c];
            for (int j = 0; j < 8; ++j) a[c][j] *= inv;
            for (int r = 0; r < 4; ++r) {
                if (r == c) continue;
                float f = a[r][c];
                for (int j = 0; j < 8; ++j) a[r][j] -= f * a[c][j];
            }
        }
        for (int r = 0; r < 3; ++r)
            for (int c = 0; c < 4; ++c)
                ti[r * 4 + c] = a[r][c + 4];
    }
    sx[threadIdx.x] = xg[threadIdx.x];
    sy[threadIdx.x] = yg[threadIdx.x];
    sz[threadIdx.x] = zg[threadIdx.x];
    __syncthreads();

    const int i0 = blockIdx.x * (blockDim.x * 2) + threadIdx.x;
    const int i1 = i0 + 256;

    // exact lower_bound via affine guess + fixup (monotone grid).
#define FIND(P, V, L, R)                                                  \
    int L, R;                                                             \
    {                                                                     \
        const float p0 = P[0];                                            \
        const float invh = 1.0f / (P[1] - p0);                            \
        int r = (int)ceilf(((V) - p0) * invh);                            \
        r = (r < 0) ? 0 : ((r > GRID_N - 1) ? GRID_N - 1 : r);            \
        while (r > 0 && P[r - 1] >= (V)) --r;                             \
        while (r < GRID_N - 1 && P[r] < (V)) ++r;                         \
        R = r;                                                            \
        L = (r > 0) ? r - 1 : 0;                                          \
    }

#define WEIGHTS(P, V, IL, IR, DL, DR)                                     \
    float DL = fmaxf((V) - P[IL], 0.0f);                                  \
    float DR = fmaxf(P[IR] - (V), 0.0f);                                  \
    if (DL == 0.0f && DR == 0.0f) { DL = 1.0f; DR = 1.0f; }

    // ---- point A ----
    float xA, yA, zA;
    int ixlA, ixrA, iylA, iyrA, izlA, izrA;
    float2u a00, a01, a10, a11;
    if (i0 < K) {
        const float px = pts[3 * i0 + 0];
        const float py = pts[3 * i0 + 1];
        const float pz = pts[3 * i0 + 2];
        xA = ti[0] * px + ti[1] * py + ti[2]  * pz + ti[3];
        yA = ti[4] * px + ti[5] * py + ti[6]  * pz + ti[7];
        zA = ti[8] * px + ti[9] * py + ti[10] * pz + ti[11];
        FIND(sx, xA, l0, r0) ixlA = l0; ixrA = r0;
        FIND(sy, yA, l1, r1) iylA = l1; iyrA = r1;
        FIND(sz, zA, l2, r2) izlA = l2; izrA = r2;
        const int bx0 = ixlA * (GRID_N * GRID_N);
        const int bx1 = ixrA * (GRID_N * GRID_N);
        const int by0 = iylA * GRID_N;
        const int by1 = iyrA * GRID_N;
        a00 = __builtin_nontemporal_load((const float2u*)(sdf + bx0 + by0 + izlA));
        a01 = __builtin_nontemporal_load((const float2u*)(sdf + bx0 + by1 + izlA));
        a10 = __builtin_nontemporal_load((const float2u*)(sdf + bx1 + by0 + izlA));
        a11 = __builtin_nontemporal_load((const float2u*)(sdf + bx1 + by1 + izlA));
    }

    // ---- point B ----
    float xB, yB, zB;
    int ixlB, ixrB, iylB, iyrB, izlB, izrB;
    float2u b00, b01, b10, b11;
    if (i1 < K) {
        const float px = pts[3 * i1 + 0];
        const float py = pts[3 * i1 + 1];
        const float pz = pts[3 * i1 + 2];
        xB = ti[0] * px + ti[1] * py + ti[2]  * pz + ti[3];
        yB = ti[4] * px + ti[5] * py + ti[6]  * pz + ti[7];
        zB = ti[8] * px + ti[9] * py + ti[10] * pz + ti[11];
        FIND(sx, xB, l0, r0) ixlB = l0; ixrB = r0;
        FIND(sy, yB, l1, r1) iylB = l1; iyrB = r1;
        FIND(sz, zB, l2, r2) izlB = l2; izrB = r2;
        const int bx0 = ixlB * (GRID_N * GRID_N);
        const int bx1 = ixrB * (GRID_N * GRID_N);
        const int by0 = iylB * GRID_N;
        const int by1 = iyrB * GRID_N;
        b00 = __builtin_nontemporal_load((const float2u*)(sdf + bx0 + by0 + izlB));
        b01 = __builtin_nontemporal_load((const float2u*)(sdf + bx0 + by1 + izlB));
        b10 = __builtin_nontemporal_load((const float2u*)(sdf + bx1 + by0 + izlB));
        b11 = __builtin_nontemporal_load((const float2u*)(sdf + bx1 + by1 + izlB));
    }

    // ---- finish A ----
    if (i0 < K) {
        WEIGHTS(sx, xA, ixlA, ixrA, dlx, drx)
        WEIGHTS(sy, yA, iylA, iyrA, dly, dry)
        WEIGHTS(sz, zA, izlA, izrA, dlz, drz)
        const bool zs = (izrA == izlA);
        const float v000 = a00.x, v001 = zs ? a00.x : a00.y;
        const float v010 = a01.x, v011 = zs ? a01.x : a01.y;
        const float v100 = a10.x, v101 = zs ? a10.x : a10.y;
        const float v110 = a11.x, v111 = zs ? a11.x : a11.y;
        const float numer =
            drx * (dry * (v000 * drz + v001 * dlz) +
                   dly * (v010 * drz + v011 * dlz)) +
            dlx * (dry * (v100 * drz + v101 * dlz) +
                   dly * (v110 * drz + v111 * dlz));
        const float denom = (dlx + drx) * (dly + dry) * (dlz + drz);
        out[i0] = numer / denom;
    }

    // ---- finish B ----
    if (i1 < K) {
        WEIGHTS(sx, xB, ixlB, ixrB, dlx, drx)
        WEIGHTS(sy, yB, iylB, iyrB, dly, dry)
        WEIGHTS(sz, zB, izlB, izrB, dlz, drz)
        const bool zs = (izrB == izlB);
        const float v000 = b00.x, v001 = zs ? b00.x : b00.y;
        const float v010 = b01.x, v011 = zs ? b01.x : b01.y;
        const float v100 = b10.x, v101 = zs ? b10.x : b10.y;
        const float v110 = b11.x, v111 = zs ? b11.x : b11.y;
        const float numer =
            drx * (dry * (v000 * drz + v001 * dlz) +
                   dly * (v010 * drz + v011 * dlz)) +
            dlx * (dry * (v100 * drz + v101 * dlz) +
                   dly * (v110 * drz + v111 * dlz));
        const float denom = (dlx + drx) * (dly + dry) * (dlz + drz);
        out[i1] = numer / denom;
    }
#undef FIND
#undef WEIGHTS
}

// ---------------------------------------------------------------------------
extern "C" void kernel_launch(void* const* d_in, const int* in_sizes, int n_in,
                              void* d_out, int out_size, void* d_ws, size_t ws_size,
                              hipStream_t stream) {
    const float* sdf  = (const float*)d_in[0];
    const float* xg   = (const float*)d_in[1];
    const float* yg   = (const float*)d_in[2];
    const float* zg   = (const float*)d_in[3];
    const float* pose = (const float*)d_in[4];
    const float* pts  = (const float*)d_in[5];
    float* out = (float*)d_out;

    const int K = in_sizes[5] / 3;

    const int block = 256;
    const int grid = (K + block * 2 - 1) / (block * 2);
    sdf_interp_kernel<<<grid, block, 0, stream>>>(sdf, xg, yg, zg, pose, pts,
                                                  out, K);
}